// Round 11
// baseline (336.607 us; speedup 1.0000x reference)
//
#include <hip/hip_runtime.h>
#include <hip/hip_bf16.h>
#include <stdint.h>

typedef unsigned long long u64;
typedef __hip_bfloat16 bf16;
typedef short s8v __attribute__((ext_vector_type(8)));
typedef short s4v __attribute__((ext_vector_type(4)));
typedef float f4v __attribute__((ext_vector_type(4)));

#define B_   16
#define C_   256
#define N_   1024
#define HID_ 512

// fp32 -> bf16 RNE, bit-level
__device__ __forceinline__ unsigned short f2b(float f) {
    unsigned u = __float_as_uint(f);
    unsigned r = (u + 0x7FFFu + ((u >> 16) & 1u)) >> 16;
    return (unsigned short)r;
}
__device__ __forceinline__ float b2f(unsigned short s) {
    return __uint_as_float(((unsigned)s) << 16);
}
// Runtime-dtype input load: bf==1 -> bf16, bf==0 -> fp32.
__device__ __forceinline__ float ldIn(const void* p, long long i, int bf) {
    return bf ? b2f(((const unsigned short*)p)[i]) : ((const float*)p)[i];
}
__device__ __forceinline__ u64 shfl_xor_u64(u64 v, int m) {
    unsigned lo = (unsigned)v, hi = (unsigned)(v >> 32);
    lo = __shfl_xor(lo, m, 64);
    hi = __shfl_xor(hi, m, 64);
    return ((u64)hi << 32) | lo;
}

// ---------------------------------------------------------------------------
// Probe input dtype + fold BN params + zero x2 accumulator.
// ---------------------------------------------------------------------------
__global__ void prep_kernel(const void* xp,
    const void* fc1_b, const void* bn1_g, const void* bn1_b, const void* bn1_m, const void* bn1_v,
    const void* gc_b,  const void* gbn_g, const void* gbn_b, const void* gbn_m, const void* gbn_v,
    const void* bn2_g, const void* bn2_b, const void* bn2_m, const void* bn2_v,
    const void* fc2_b, const void* bn3_g, const void* bn3_b, const void* bn3_m, const void* bn3_v,
    int* flags, float* s1, float* t1, float* Sg, float* Tg, float* s3, float* t3,
    float* x2)
{
    __shared__ int sf;
    if (threadIdx.x == 0) {
        const unsigned short* u = (const unsigned short*)xp;
        int cnt = 0;
        for (int i = 0; i < 64; ++i) {
            int e = (u[2 * i] >> 7) & 0xFF;
            cnt += (e >= 87 && e <= 167);
        }
        int f = (cnt >= 48) ? 1 : 0;
        flags[0] = f;
        sf = f;
    }
    // zero the x2 accumulator (ws is poisoned 0xAA before every launch)
    for (int i = threadIdx.x; i < B_ * N_; i += 512) x2[i] = 0.f;
    __syncthreads();
    int bf = sf;
    int i = threadIdx.x;
    if (i < 256) {
        float g = ldIn(bn1_g, i, bf), bb = ldIn(bn1_b, i, bf);
        float m = ldIn(bn1_m, i, bf), v  = ldIn(bn1_v, i, bf);
        float s = g / sqrtf(v + 1e-5f);
        s1[i] = s;
        t1[i] = (ldIn(fc1_b, i, bf) - m) * s + bb;

        float g3 = ldIn(bn3_g, i, bf), b3 = ldIn(bn3_b, i, bf);
        float m3 = ldIn(bn3_m, i, bf), v3 = ldIn(bn3_v, i, bf);
        float ss3 = g3 / sqrtf(v3 + 1e-5f);
        s3[i] = ss3;
        t3[i] = (ldIn(fc2_b, i, bf) - m3) * ss3 + b3;
    }
    if (i < 512) {
        float gg = ldIn(gbn_g, i, bf), gb = ldIn(gbn_b, i, bf);
        float gm = ldIn(gbn_m, i, bf), gv = ldIn(gbn_v, i, bf);
        float sg = gg / sqrtf(gv + 1e-5f);
        float g2 = ldIn(bn2_g, i, bf), b2 = ldIn(bn2_b, i, bf);
        float m2 = ldIn(bn2_m, i, bf), v2 = ldIn(bn2_v, i, bf);
        float s2 = g2 / sqrtf(v2 + 1e-5f);
        Sg[i] = sg * s2;
        Tg[i] = ((ldIn(gc_b, i, bf) - gm) * sg + gb - m2) * s2 + b2;
    }
}

// ---------------------------------------------------------------------------
// Weights: gc/fc2 -> bf16 (fc1 stays fp32-VALU).
// ---------------------------------------------------------------------------
__global__ __launch_bounds__(256)
void cast_weights(const void* w1, const void* wg, const void* w2,
                  short* W1b, short* Wgb, short* W2b, const int* flags)
{
    int inf = flags[0];
    int i = blockIdx.x * 256 + threadIdx.x;
    if (i < 65536) {
        W1b[i] = (short)f2b(ldIn(w1, i, inf));
    } else if (i < 65536 + 262144) {
        int j = i - 65536;
        Wgb[j] = (short)f2b(ldIn(wg, j, inf));
    } else {
        int j = i - 327680;
        W2b[j] = (short)f2b(ldIn(w2, j, inf));
    }
}

// ---------------------------------------------------------------------------
// fc1 (VALU fp32, known-good main loop) + FUSED epilogue:
//   writes Ft fp32, Fhi/Flo bf16 split, and x2 (block-partial + atomicAdd).
// ---------------------------------------------------------------------------
__global__ __launch_bounds__(256)
void fc1_valu(const void* __restrict__ Aw, const void* __restrict__ Bx,
              float* __restrict__ Ft, short* __restrict__ Fhi,
              short* __restrict__ Flo, float* __restrict__ x2,
              const float* __restrict__ s1, const float* __restrict__ t1,
              const int* __restrict__ flags)
{
    __shared__ float As[16][68];
    __shared__ float Bs[16][68];
    __shared__ float x2part[16][64];

    int inf = flags[0];
    int b  = blockIdx.z;
    int o0 = blockIdx.y * 64, n0 = blockIdx.x * 64;
    int t  = threadIdx.x;
    int tn = t & 15, to = t >> 4;
    long long bbase = (long long)b * C_ * N_;

    float acc[4][4] = {};

    for (int k0 = 0; k0 < C_; k0 += 16) {
        {
            int l = t * 4;
            int ao = l >> 4, ak = l & 15;
            long long ai = (long long)(o0 + ao) * C_ + k0 + ak;
            As[ak + 0][ao] = ldIn(Aw, ai + 0, inf);
            As[ak + 1][ao] = ldIn(Aw, ai + 1, inf);
            As[ak + 2][ao] = ldIn(Aw, ai + 2, inf);
            As[ak + 3][ao] = ldIn(Aw, ai + 3, inf);
        }
        {
            int l = t * 4;
            int bk = l >> 6, bn = l & 63;
            long long bi = bbase + (long long)(k0 + bk) * N_ + n0 + bn;
            Bs[bk][bn + 0] = ldIn(Bx, bi + 0, inf);
            Bs[bk][bn + 1] = ldIn(Bx, bi + 1, inf);
            Bs[bk][bn + 2] = ldIn(Bx, bi + 2, inf);
            Bs[bk][bn + 3] = ldIn(Bx, bi + 3, inf);
        }
        __syncthreads();
        #pragma unroll
        for (int k = 0; k < 16; ++k) {
            float av[4], bv[4];
            #pragma unroll
            for (int i = 0; i < 4; ++i) av[i] = As[k][to * 4 + i];
            #pragma unroll
            for (int j = 0; j < 4; ++j) bv[j] = Bs[k][tn * 4 + j];
            #pragma unroll
            for (int i = 0; i < 4; ++i)
                #pragma unroll
                for (int j = 0; j < 4; ++j) acc[i][j] += av[i] * bv[j];
        }
        __syncthreads();
    }

    float p2[4] = {};
    #pragma unroll
    for (int i = 0; i < 4; ++i) {
        int o = o0 + to * 4 + i;
        float s = s1[o], tt = t1[o];
        #pragma unroll
        for (int j = 0; j < 4; ++j) {
            int n = n0 + tn * 4 + j;
            float f = acc[i][j] * s + tt;
            long long oi = ((long long)(b << 10) + n) * C_ + o;
            Ft[oi] = f;
            unsigned short h = f2b(f);
            Fhi[oi] = (short)h;
            Flo[oi] = (short)f2b(f - b2f(h));
            p2[j] += f * f;
        }
    }
    #pragma unroll
    for (int j = 0; j < 4; ++j) x2part[to][tn * 4 + j] = p2[j];
    __syncthreads();
    if (t < 64) {
        float s = 0.f;
        #pragma unroll
        for (int r = 0; r < 16; ++r) s += x2part[r][t];
        atomicAdd(&x2[(b << 10) + n0 + t], s);
    }
}

// ---------------------------------------------------------------------------
// Fused gram + top-9 v4 (occupancy-tuned register scan).
// Block: 64 q x 128 m. grid (16 q, 8 mq, 16 b) = 2048 blocks. LDS 31.2 KB.
// A-operand = m, B-operand = q: lane's C-col = fixed q, rows = m -> ladder
// runs on accumulators. 3-pass hi/lo split (lo*lo dropped).
// In-block merge (quads -> pairs -> one) -> Part[row][mq][9].
// ---------------------------------------------------------------------------
__global__ __launch_bounds__(256)
void gram_topk(const short* __restrict__ Fhi, const short* __restrict__ Flo,
               const float* __restrict__ x2, u64* __restrict__ Part)
{
    __shared__ __align__(16) char ldsbuf[31232];
    short* Ah  = (short*)(ldsbuf);             // [128][40] m hi
    short* Al  = (short*)(ldsbuf + 10240);     // [128][40] m lo
    short* Bh  = (short*)(ldsbuf + 20480);     // [64][40]  q hi
    short* Bl  = (short*)(ldsbuf + 25600);     // [64][40]  q lo
    float* x2s = (float*)(ldsbuf + 30720);     // [128]
    u64*   mrg  = (u64*)(ldsbuf);              // overlay Ah/Al: 64*4*9*8=18432
    u64*   mrg2 = (u64*)(ldsbuf + 20480);      // overlay Bh/Bl: 64*2*9*8=9216

    int t = threadIdx.x;
    int q0 = blockIdx.x * 64, mq = blockIdx.y, b = blockIdx.z;
    int wv = t >> 6, ln15 = t & 15, quad = (t >> 4) & 3;

    if (t < 128) x2s[t] = x2[(b << 10) + mq * 128 + t];

    f4v acc[8];
    #pragma unroll
    for (int i = 0; i < 8; ++i) acc[i] = 0.f;

    for (int kc = 0; kc < 8; ++kc) {
        __syncthreads();
        // stage 384 rows: A 128 hi + 128 lo (m), B 64 hi + 64 lo (q)
        #pragma unroll
        for (int s = 0; s < 6; ++s) {
            int sid = t + s * 256;            // 0..1535
            int row = sid >> 2, seg = sid & 3;
            const short* src;
            short* dst;
            int grow;
            if (row < 128)      { dst = &Ah[row * 40 + seg * 8];         grow = mq * 128 + row;       src = Fhi; }
            else if (row < 256) { dst = &Al[(row - 128) * 40 + seg * 8]; grow = mq * 128 + row - 128; src = Flo; }
            else if (row < 320) { dst = &Bh[(row - 256) * 40 + seg * 8]; grow = q0 + row - 256;       src = Fhi; }
            else                { dst = &Bl[(row - 320) * 40 + seg * 8]; grow = q0 + row - 320;       src = Flo; }
            *(s8v*)dst = *(const s8v*)(src + ((long long)((b << 10) + grow)) * C_ + kc * 32 + seg * 8);
        }
        __syncthreads();
        s8v qh = *(s8v*)&Bh[(wv * 16 + ln15) * 40 + quad * 8];
        s8v ql = *(s8v*)&Bl[(wv * 16 + ln15) * 40 + quad * 8];
        #pragma unroll
        for (int i = 0; i < 8; ++i) {
            s8v mh = *(s8v*)&Ah[(i * 16 + ln15) * 40 + quad * 8];
            s8v ml = *(s8v*)&Al[(i * 16 + ln15) * 40 + quad * 8];
            acc[i] = __builtin_amdgcn_mfma_f32_16x16x32_bf16(mh, qh, acc[i], 0, 0, 0);
            acc[i] = __builtin_amdgcn_mfma_f32_16x16x32_bf16(mh, ql, acc[i], 0, 0, 0);
            acc[i] = __builtin_amdgcn_mfma_f32_16x16x32_bf16(ml, qh, acc[i], 0, 0, 0);
        }
    }

    // register ladder: lane's q = q0 + wv*16 + ln15; m = mq*128 + i*16 + quad*4 + r
    u64 l[9];
    #pragma unroll
    for (int i = 0; i < 9; ++i) l[i] = ~0ULL;
    #pragma unroll
    for (int i = 0; i < 8; ++i) {
        #pragma unroll
        for (int r = 0; r < 4; ++r) {
            int mloc = i * 16 + quad * 4 + r;
            float d = x2s[mloc] - 2.f * acc[i][r];
            unsigned u = __float_as_uint(d);
            u = (u & 0x80000000u) ? ~u : (u | 0x80000000u);
            u64 key = ((u64)u << 32) | (unsigned)(mq * 128 + mloc);
            if (key < l[8]) {
                u64 x = key;
                #pragma unroll
                for (int jj = 0; jj < 9; ++jj) {
                    u64 lo2 = l[jj] < x ? l[jj] : x;
                    u64 hi2 = l[jj] < x ? x : l[jj];
                    l[jj] = lo2; x = hi2;
                }
            }
        }
    }

    __syncthreads();   // all LDS reads done before overlay
    {
        int qloc = wv * 16 + ln15;
        #pragma unroll
        for (int k = 0; k < 9; ++k) mrg[(qloc * 4 + quad) * 9 + k] = l[k];
    }
    __syncthreads();
    if (t < 128) {
        int r = t >> 1, pr = t & 1;
        const u64* LA = &mrg[(r * 4 + pr * 2) * 9];
        const u64* LB = LA + 9;
        int ia = 0, ib = 0;
        u64* Po = &mrg2[(r * 2 + pr) * 9];
        #pragma unroll
        for (int k = 0; k < 9; ++k) {
            u64 va = LA[ia], vb = LB[ib];
            bool ta = va < vb;
            Po[k] = ta ? va : vb;
            ia += ta; ib += !ta;
        }
    }
    __syncthreads();
    if (t < 64) {
        const u64* LA = &mrg2[(t * 2) * 9];
        const u64* LB = LA + 9;
        int ia = 0, ib = 0;
        u64* P = Part + (((long long)((b << 10) + q0 + t)) * 8 + mq) * 9;
        #pragma unroll
        for (int k = 0; k < 9; ++k) {
            u64 va = LA[ia], vb = LB[ib];
            bool ta = va < vb;
            P[k] = ta ? va : vb;
            ia += ta; ib += !ta;
        }
    }
}

// ---------------------------------------------------------------------------
// build_Mt + FUSED 8-list merge. One wave per n. Lane i loads partial list
// (i&7); 3 shfl_xor ladder-merge rounds -> every lane holds the global
// top-9. Then gather + interleave as before.
// ---------------------------------------------------------------------------
__global__ __launch_bounds__(256)
void build_Mt(const float* __restrict__ Ft, const u64* __restrict__ Part,
              short* __restrict__ Mt)
{
    int t = threadIdx.x;
    int wv = t >> 6, lane = t & 63;
    int n = blockIdx.x * 4 + wv;
    int b = blockIdx.y;
    long long nb = (long long)(b << 10) + n;

    // merge 8 sorted 9-lists (ties/order preserved by u64 key compare)
    const u64* L = Part + nb * 72 + (long long)(lane & 7) * 9;
    u64 l[9];
    #pragma unroll
    for (int k = 0; k < 9; ++k) l[k] = L[k];
    #pragma unroll
    for (int s = 1; s <= 4; s <<= 1) {
        u64 p[9];
        #pragma unroll
        for (int k = 0; k < 9; ++k) p[k] = shfl_xor_u64(l[k], s);
        #pragma unroll
        for (int k = 0; k < 9; ++k) {
            u64 x = p[k];
            if (x < l[8]) {
                #pragma unroll
                for (int jj = 0; jj < 9; ++jj) {
                    u64 lo2 = l[jj] < x ? l[jj] : x;
                    u64 hi2 = l[jj] < x ? x : l[jj];
                    l[jj] = lo2; x = hi2;
                }
            }
        }
    }
    // every lane now holds the identical global top-9 (sorted)

    int c0 = lane * 4;
    f4v f = *(const f4v*)(Ft + nb * C_ + c0);
    f4v mx = {-3.4e38f, -3.4e38f, -3.4e38f, -3.4e38f};
    #pragma unroll
    for (int k = 0; k < 9; ++k) {
        int id = (int)(l[k] & 0xFFFFFFFFu);
        f4v g = *(const f4v*)(Ft + ((long long)(b << 10) + id) * C_ + c0);
        mx[0] = fmaxf(mx[0], g[0]); mx[1] = fmaxf(mx[1], g[1]);
        mx[2] = fmaxf(mx[2], g[2]); mx[3] = fmaxf(mx[3], g[3]);
    }
    s8v m8;
    #pragma unroll
    for (int r = 0; r < 4; ++r) {
        m8[2 * r]     = (short)f2b(f[r]);
        m8[2 * r + 1] = (short)f2b(mx[r] - f[r]);
    }
    *(s8v*)(Mt + nb * (2 * C_) + 2 * c0) = m8;
}

// ---------------------------------------------------------------------------
// MFMA GEMM (known-good): acc[o][n] = sum_k A[o][k] * Bm[b][n][k]
// EPI 0: gelu(acc*s+t) -> bf16 Gt[b][n][Odim]
// EPI 1: acc*s+t + resid -> fp32 out[b][o][1024]
// ---------------------------------------------------------------------------
template<int EPI>
__global__ __launch_bounds__(256)
void mfma_gemm(const short* __restrict__ A, const short* __restrict__ Bm,
               void* __restrict__ Out, const float* __restrict__ scale,
               const float* __restrict__ bias, const void* __restrict__ resid,
               const int* __restrict__ flags, int K, int Odim)
{
    __shared__ short As[128][40];
    __shared__ short Bs[128][40];

    int t = threadIdx.x, b = blockIdx.z;
    int n0 = blockIdx.x * 128, o0 = blockIdx.y * 128;
    int wv = t >> 6, ln = t & 15, quad = (t >> 4) & 3;
    int wo = (wv & 1) * 64, wn = (wv >> 1) * 64;

    f4v acc[4][4];
    #pragma unroll
    for (int i = 0; i < 4; ++i)
        #pragma unroll
        for (int j = 0; j < 4; ++j) acc[i][j] = 0.f;

    const short* Ab = A + (long long)o0 * K;
    const short* Bb = Bm + ((long long)(b << 10) + n0) * K;

    for (int k0 = 0; k0 < K; k0 += 32) {
        __syncthreads();
        #pragma unroll
        for (int s = 0; s < 2; ++s) {
            int sid = t + s * 256;
            int row = sid >> 2, seg = sid & 3;
            *(s8v*)&As[row][seg * 8] = *(const s8v*)(Ab + (long long)row * K + k0 + seg * 8);
            *(s8v*)&Bs[row][seg * 8] = *(const s8v*)(Bb + (long long)row * K + k0 + seg * 8);
        }
        __syncthreads();
        s8v a[4], bf[4];
        #pragma unroll
        for (int i = 0; i < 4; ++i) a[i]  = *(s8v*)&As[wo + i * 16 + ln][quad * 8];
        #pragma unroll
        for (int j = 0; j < 4; ++j) bf[j] = *(s8v*)&Bs[wn + j * 16 + ln][quad * 8];
        #pragma unroll
        for (int i = 0; i < 4; ++i)
            #pragma unroll
            for (int j = 0; j < 4; ++j)
                acc[i][j] = __builtin_amdgcn_mfma_f32_16x16x32_bf16(a[i], bf[j], acc[i][j], 0, 0, 0);
    }

    int inf = flags[0];
    #pragma unroll
    for (int i = 0; i < 4; ++i) {
        int ob = o0 + wo + i * 16 + quad * 4;
        #pragma unroll
        for (int j = 0; j < 4; ++j) {
            int n = n0 + wn + j * 16 + ln;
            f4v v = acc[i][j];
            if (EPI == 0) {
                s4v g;
                #pragma unroll
                for (int r = 0; r < 4; ++r) {
                    float val = v[r] * scale[ob + r] + bias[ob + r];
                    val = 0.5f * val * (1.0f + erff(val * 0.70710678118654752f));
                    g[r] = (short)f2b(val);
                }
                *(s4v*)((short*)Out + ((long long)(b << 10) + n) * Odim + ob) = g;
            } else {
                #pragma unroll
                for (int r = 0; r < 4; ++r) {
                    int o = ob + r;
                    long long oi = ((long long)b * Odim + o) * N_ + n;
                    ((float*)Out)[oi] = v[r] * scale[o] + bias[o] + ldIn(resid, oi, inf);
                }
            }
        }
    }
}

// ---------------------------------------------------------------------------
extern "C" void kernel_launch(void* const* d_in, const int* in_sizes, int n_in,
                              void* d_out, int out_size, void* d_ws, size_t ws_size,
                              hipStream_t stream)
{
    const void* p[23];
    if (n_in >= 23 && in_sizes[0] != 4194304 && in_sizes[22] == 4194304) {
        const int amap[23] = {
            22, 13, 12, 1, 0, 2, 3,
            21, 20, 17, 16, 18, 19,
            5, 4, 6, 7,
            15, 14, 9, 8, 10, 11 };
        for (int i = 0; i < 23; ++i) p[i] = d_in[amap[i]];
    } else {
        for (int i = 0; i < 23; ++i) p[i] = d_in[i];
    }

    const void* x     = p[0];
    const void* fc1_w = p[1];
    const void* fc1_b = p[2];
    const void* bn1_g = p[3];
    const void* bn1_b = p[4];
    const void* bn1_m = p[5];
    const void* bn1_v = p[6];
    const void* gc_w  = p[7];
    const void* gc_b  = p[8];
    const void* gbn_g = p[9];
    const void* gbn_b = p[10];
    const void* gbn_m = p[11];
    const void* gbn_v = p[12];
    const void* bn2_g = p[13];
    const void* bn2_b = p[14];
    const void* bn2_m = p[15];
    const void* bn2_v = p[16];
    const void* fc2_w = p[17];
    const void* fc2_b = p[18];
    const void* bn3_g = p[19];
    const void* bn3_b = p[20];
    const void* bn3_m = p[21];
    const void* bn3_v = p[22];

    char* ws = (char*)d_ws;
    size_t off = 0;
    int*   flags = (int*)ws;
    float* s1 = (float*)(ws + 256);
    float* t1 = s1 + 256;
    float* s3 = t1 + 256;
    float* t3 = s3 + 256;
    float* Sg = t3 + 256;
    float* Tg = Sg + 512;
    off = 16384;
    short* W1b   = (short*)(ws + off); off += (size_t)C_ * C_ * 2;          // 128 KiB
    short* Wgb   = (short*)(ws + off); off += (size_t)HID_ * 2 * C_ * 2;    // 512 KiB
    short* W2b   = (short*)(ws + off); off += (size_t)C_ * HID_ * 2;        // 256 KiB
    float* Ft    = (float*)(ws + off); off += (size_t)B_ * N_ * C_ * 4;     // 16 MiB
    short* Fhi   = (short*)(ws + off); off += (size_t)B_ * N_ * C_ * 2;     // 8 MiB
    short* Flo   = (short*)(ws + off); off += (size_t)B_ * N_ * C_ * 2;     // 8 MiB
    float* x2    = (float*)(ws + off); off += (size_t)B_ * N_ * 4;          // 64 KiB
    u64*   Part  = (u64*)  (ws + off); off += (size_t)B_ * N_ * 8 * 9 * 8;  // 9 MiB
    short* Mt    = (short*)(ws + off); off += (size_t)B_ * N_ * 2 * C_ * 2; // 16 MiB
    short* Gt    = (short*)(ws + off); off += (size_t)B_ * N_ * HID_ * 2;   // 16 MiB

    prep_kernel<<<1, 512, 0, stream>>>(x,
        fc1_b, bn1_g, bn1_b, bn1_m, bn1_v,
        gc_b, gbn_g, gbn_b, gbn_m, gbn_v,
        bn2_g, bn2_b, bn2_m, bn2_v,
        fc2_b, bn3_g, bn3_b, bn3_m, bn3_v,
        flags, s1, t1, Sg, Tg, s3, t3, x2);

    cast_weights<<<1792, 256, 0, stream>>>(fc1_w, gc_w, fc2_w,
                                           W1b, Wgb, W2b, flags);

    // fc1 + BN1 -> Ft, Fhi/Flo, x2 (fused)
    fc1_valu<<<dim3(16, 4, B_), 256, 0, stream>>>(
        fc1_w, x, Ft, Fhi, Flo, x2, s1, t1, flags);

    gram_topk<<<dim3(16, 8, 16), 256, 0, stream>>>(Fhi, Flo, x2, Part);

    build_Mt<<<dim3(256, 16), 256, 0, stream>>>(Ft, Part, Mt);

    mfma_gemm<0><<<dim3(8, 4, 16), 256, 0, stream>>>(
        Wgb, Mt, Gt, Sg, Tg, nullptr, flags, 2 * C_, HID_);

    mfma_gemm<1><<<dim3(8, 2, 16), 256, 0, stream>>>(
        W2b, Gt, d_out, s3, t3, x, flags, HID_, C_);
}

// Round 12
// 304.411 us; speedup vs baseline: 1.1058x; 1.1058x over previous
//
#include <hip/hip_runtime.h>
#include <hip/hip_bf16.h>
#include <stdint.h>

typedef unsigned long long u64;
typedef __hip_bfloat16 bf16;
typedef short s8v __attribute__((ext_vector_type(8)));
typedef short s4v __attribute__((ext_vector_type(4)));
typedef float f4v __attribute__((ext_vector_type(4)));

#define B_   16
#define C_   256
#define N_   1024
#define HID_ 512

// fp32 -> bf16 RNE, bit-level
__device__ __forceinline__ unsigned short f2b(float f) {
    unsigned u = __float_as_uint(f);
    unsigned r = (u + 0x7FFFu + ((u >> 16) & 1u)) >> 16;
    return (unsigned short)r;
}
__device__ __forceinline__ float b2f(unsigned short s) {
    return __uint_as_float(((unsigned)s) << 16);
}
// Runtime-dtype input load: bf==1 -> bf16, bf==0 -> fp32.
__device__ __forceinline__ float ldIn(const void* p, long long i, int bf) {
    return bf ? b2f(((const unsigned short*)p)[i]) : ((const float*)p)[i];
}
__device__ __forceinline__ u64 shfl_xor_u64(u64 v, int m) {
    unsigned lo = (unsigned)v, hi = (unsigned)(v >> 32);
    lo = __shfl_xor(lo, m, 64);
    hi = __shfl_xor(hi, m, 64);
    return ((u64)hi << 32) | lo;
}

// ---------------------------------------------------------------------------
// Probe input dtype + fold BN params + zero x2 accumulator.
// ---------------------------------------------------------------------------
__global__ void prep_kernel(const void* xp,
    const void* fc1_b, const void* bn1_g, const void* bn1_b, const void* bn1_m, const void* bn1_v,
    const void* gc_b,  const void* gbn_g, const void* gbn_b, const void* gbn_m, const void* gbn_v,
    const void* bn2_g, const void* bn2_b, const void* bn2_m, const void* bn2_v,
    const void* fc2_b, const void* bn3_g, const void* bn3_b, const void* bn3_m, const void* bn3_v,
    int* flags, float* s1, float* t1, float* Sg, float* Tg, float* s3, float* t3,
    float* x2)
{
    __shared__ int sf;
    if (threadIdx.x == 0) {
        const unsigned short* u = (const unsigned short*)xp;
        int cnt = 0;
        for (int i = 0; i < 64; ++i) {
            int e = (u[2 * i] >> 7) & 0xFF;
            cnt += (e >= 87 && e <= 167);
        }
        int f = (cnt >= 48) ? 1 : 0;
        flags[0] = f;
        sf = f;
    }
    for (int i = threadIdx.x; i < B_ * N_; i += 512) x2[i] = 0.f;
    __syncthreads();
    int bf = sf;
    int i = threadIdx.x;
    if (i < 256) {
        float g = ldIn(bn1_g, i, bf), bb = ldIn(bn1_b, i, bf);
        float m = ldIn(bn1_m, i, bf), v  = ldIn(bn1_v, i, bf);
        float s = g / sqrtf(v + 1e-5f);
        s1[i] = s;
        t1[i] = (ldIn(fc1_b, i, bf) - m) * s + bb;

        float g3 = ldIn(bn3_g, i, bf), b3 = ldIn(bn3_b, i, bf);
        float m3 = ldIn(bn3_m, i, bf), v3 = ldIn(bn3_v, i, bf);
        float ss3 = g3 / sqrtf(v3 + 1e-5f);
        s3[i] = ss3;
        t3[i] = (ldIn(fc2_b, i, bf) - m3) * ss3 + b3;
    }
    if (i < 512) {
        float gg = ldIn(gbn_g, i, bf), gb = ldIn(gbn_b, i, bf);
        float gm = ldIn(gbn_m, i, bf), gv = ldIn(gbn_v, i, bf);
        float sg = gg / sqrtf(gv + 1e-5f);
        float g2 = ldIn(bn2_g, i, bf), b2 = ldIn(bn2_b, i, bf);
        float m2 = ldIn(bn2_m, i, bf), v2 = ldIn(bn2_v, i, bf);
        float s2 = g2 / sqrtf(v2 + 1e-5f);
        Sg[i] = sg * s2;
        Tg[i] = ((ldIn(gc_b, i, bf) - gm) * sg + gb - m2) * s2 + b2;
    }
}

// ---------------------------------------------------------------------------
// Weights: fc1 -> hi/lo split bf16 (feeds split-MFMA); gc/fc2 -> single bf16.
// ---------------------------------------------------------------------------
__global__ __launch_bounds__(256)
void cast_weights(const void* w1, const void* wg, const void* w2,
                  short* W1h, short* W1l, short* Wgb, short* W2b,
                  const int* flags)
{
    int inf = flags[0];
    int i = blockIdx.x * 256 + threadIdx.x;
    if (i < 65536) {
        float f = ldIn(w1, i, inf);
        unsigned short h = f2b(f);
        W1h[i] = (short)h;
        W1l[i] = (short)f2b(f - b2f(h));
    } else if (i < 65536 + 262144) {
        int j = i - 65536;
        Wgb[j] = (short)f2b(ldIn(wg, j, inf));
    } else {
        int j = i - 327680;
        W2b[j] = (short)f2b(ldIn(w2, j, inf));
    }
}

// ---------------------------------------------------------------------------
// transpose_split_x: x[b][c][n] -> xth/xtl[b][n][c] (bf16 hi/lo split).
// 64c x 64n tile via LDS. grid (16 n-tiles, 4 c-tiles, 16 b).
// ---------------------------------------------------------------------------
__global__ __launch_bounds__(256)
void transpose_split_x(const void* __restrict__ X, short* __restrict__ xth,
                       short* __restrict__ xtl, const int* __restrict__ flags)
{
    __shared__ float tile[64][68];
    int inf = flags[0];
    int t = threadIdx.x;
    int n0 = blockIdx.x * 64, c0 = blockIdx.y * 64, b = blockIdx.z;

    #pragma unroll
    for (int rr = 0; rr < 4; ++rr) {
        int cl = (t >> 4) + rr * 16;
        int nl = (t & 15) * 4;
        long long g = ((long long)b * C_ + c0 + cl) * N_ + n0 + nl;
        if (inf) {
            s4v v = *(const s4v*)((const short*)X + g);
            tile[cl][nl + 0] = b2f((unsigned short)v[0]);
            tile[cl][nl + 1] = b2f((unsigned short)v[1]);
            tile[cl][nl + 2] = b2f((unsigned short)v[2]);
            tile[cl][nl + 3] = b2f((unsigned short)v[3]);
        } else {
            f4v v = *(const f4v*)((const float*)X + g);
            tile[cl][nl + 0] = v[0]; tile[cl][nl + 1] = v[1];
            tile[cl][nl + 2] = v[2]; tile[cl][nl + 3] = v[3];
        }
    }
    __syncthreads();

    int nl = t >> 2, cseg = t & 3;   // thread covers 16 c for one n
    long long base = ((long long)((b << 10) + n0 + nl)) * C_ + c0 + cseg * 16;
    s8v h0, h1, l0, l1;
    #pragma unroll
    for (int cc = 0; cc < 16; ++cc) {
        float f = tile[cseg * 16 + cc][nl];
        unsigned short h = f2b(f);
        unsigned short l = f2b(f - b2f(h));
        if (cc < 8) { h0[cc] = (short)h; l0[cc] = (short)l; }
        else        { h1[cc - 8] = (short)h; l1[cc - 8] = (short)l; }
    }
    *(s8v*)(xth + base)     = h0;
    *(s8v*)(xth + base + 8) = h1;
    *(s8v*)(xtl + base)     = l0;
    *(s8v*)(xtl + base + 8) = l1;
}

// ---------------------------------------------------------------------------
// fc1 split-MFMA (gram-v4 skeleton transplant):
//   Ft[b][n][o] = s1[o]*(sum_c x^T[n][c]*W1[o][c]) + t1[o]
// A-operand = W rows (o, 128/block), B-operand = x^T rows (n, 64/block).
// Lane's C-col = fixed n; rows = o. 3-pass hi/lo (lo*lo dropped).
// Epilogue: Ft fp32 + Fhi/Flo split + x2 (quad-shuffle reduce + atomicAdd).
// grid (16 n, 2 o-half, 16 b) = 512 blocks. LDS 30.7 KB.
// ---------------------------------------------------------------------------
__global__ __launch_bounds__(256)
void fc1_mfma(const short* __restrict__ W1h, const short* __restrict__ W1l,
              const short* __restrict__ xth, const short* __restrict__ xtl,
              const float* __restrict__ s1, const float* __restrict__ t1,
              float* __restrict__ Ft, short* __restrict__ Fhi,
              short* __restrict__ Flo, float* __restrict__ x2)
{
    __shared__ __align__(16) char ldsbuf[30720];
    short* Wh = (short*)(ldsbuf);             // [128][40] o hi
    short* Wl = (short*)(ldsbuf + 10240);     // [128][40] o lo
    short* Xh = (short*)(ldsbuf + 20480);     // [64][40]  n hi
    short* Xl = (short*)(ldsbuf + 25600);     // [64][40]  n lo

    int t = threadIdx.x;
    int n0 = blockIdx.x * 64, o0 = blockIdx.y * 128, b = blockIdx.z;
    int wv = t >> 6, ln15 = t & 15, quad = (t >> 4) & 3;

    f4v acc[8];
    #pragma unroll
    for (int i = 0; i < 8; ++i) acc[i] = 0.f;

    for (int kc = 0; kc < 8; ++kc) {
        __syncthreads();
        #pragma unroll
        for (int s = 0; s < 6; ++s) {
            int sid = t + s * 256;            // 0..1535
            int row = sid >> 2, seg = sid & 3;
            const short* src;
            short* dst;
            if (row < 128)      { dst = &Wh[row * 40 + seg * 8];         src = W1h + (long long)(o0 + row) * C_; }
            else if (row < 256) { dst = &Wl[(row - 128) * 40 + seg * 8]; src = W1l + (long long)(o0 + row - 128) * C_; }
            else if (row < 320) { dst = &Xh[(row - 256) * 40 + seg * 8]; src = xth + ((long long)((b << 10) + n0 + row - 256)) * C_; }
            else                { dst = &Xl[(row - 320) * 40 + seg * 8]; src = xtl + ((long long)((b << 10) + n0 + row - 320)) * C_; }
            *(s8v*)dst = *(const s8v*)(src + kc * 32 + seg * 8);
        }
        __syncthreads();
        s8v xh8 = *(s8v*)&Xh[(wv * 16 + ln15) * 40 + quad * 8];
        s8v xl8 = *(s8v*)&Xl[(wv * 16 + ln15) * 40 + quad * 8];
        #pragma unroll
        for (int i = 0; i < 8; ++i) {
            s8v wh8 = *(s8v*)&Wh[(i * 16 + ln15) * 40 + quad * 8];
            s8v wl8 = *(s8v*)&Wl[(i * 16 + ln15) * 40 + quad * 8];
            acc[i] = __builtin_amdgcn_mfma_f32_16x16x32_bf16(wh8, xh8, acc[i], 0, 0, 0);
            acc[i] = __builtin_amdgcn_mfma_f32_16x16x32_bf16(wh8, xl8, acc[i], 0, 0, 0);
            acc[i] = __builtin_amdgcn_mfma_f32_16x16x32_bf16(wl8, xh8, acc[i], 0, 0, 0);
        }
    }

    // lane's n = n0 + wv*16 + ln15; o = o0 + i*16 + quad*4 + r
    int n = n0 + wv * 16 + ln15;
    long long nb = (long long)(b << 10) + n;
    float p2 = 0.f;
    #pragma unroll
    for (int i = 0; i < 8; ++i) {
        int ob = o0 + i * 16 + quad * 4;
        f4v f;
        s4v hi, lo;
        #pragma unroll
        for (int r = 0; r < 4; ++r) {
            float v = acc[i][r] * s1[ob + r] + t1[ob + r];
            f[r] = v;
            unsigned short h = f2b(v);
            hi[r] = (short)h;
            lo[r] = (short)f2b(v - b2f(h));
            p2 += v * v;
        }
        *(f4v*)(Ft  + nb * C_ + ob) = f;
        *(s4v*)(Fhi + nb * C_ + ob) = hi;
        *(s4v*)(Flo + nb * C_ + ob) = lo;
    }
    p2 += __shfl_xor(p2, 16, 64);
    p2 += __shfl_xor(p2, 32, 64);
    if (quad == 0) atomicAdd(&x2[nb], p2);
}

// ---------------------------------------------------------------------------
// Fused gram + top-9 v4 (UNCHANGED from R11 — verified).
// ---------------------------------------------------------------------------
__global__ __launch_bounds__(256)
void gram_topk(const short* __restrict__ Fhi, const short* __restrict__ Flo,
               const float* __restrict__ x2, u64* __restrict__ Part)
{
    __shared__ __align__(16) char ldsbuf[31232];
    short* Ah  = (short*)(ldsbuf);
    short* Al  = (short*)(ldsbuf + 10240);
    short* Bh  = (short*)(ldsbuf + 20480);
    short* Bl  = (short*)(ldsbuf + 25600);
    float* x2s = (float*)(ldsbuf + 30720);
    u64*   mrg  = (u64*)(ldsbuf);
    u64*   mrg2 = (u64*)(ldsbuf + 20480);

    int t = threadIdx.x;
    int q0 = blockIdx.x * 64, mq = blockIdx.y, b = blockIdx.z;
    int wv = t >> 6, ln15 = t & 15, quad = (t >> 4) & 3;

    if (t < 128) x2s[t] = x2[(b << 10) + mq * 128 + t];

    f4v acc[8];
    #pragma unroll
    for (int i = 0; i < 8; ++i) acc[i] = 0.f;

    for (int kc = 0; kc < 8; ++kc) {
        __syncthreads();
        #pragma unroll
        for (int s = 0; s < 6; ++s) {
            int sid = t + s * 256;
            int row = sid >> 2, seg = sid & 3;
            const short* src;
            short* dst;
            int grow;
            if (row < 128)      { dst = &Ah[row * 40 + seg * 8];         grow = mq * 128 + row;       src = Fhi; }
            else if (row < 256) { dst = &Al[(row - 128) * 40 + seg * 8]; grow = mq * 128 + row - 128; src = Flo; }
            else if (row < 320) { dst = &Bh[(row - 256) * 40 + seg * 8]; grow = q0 + row - 256;       src = Fhi; }
            else                { dst = &Bl[(row - 320) * 40 + seg * 8]; grow = q0 + row - 320;       src = Flo; }
            *(s8v*)dst = *(const s8v*)(src + ((long long)((b << 10) + grow)) * C_ + kc * 32 + seg * 8);
        }
        __syncthreads();
        s8v qh = *(s8v*)&Bh[(wv * 16 + ln15) * 40 + quad * 8];
        s8v ql = *(s8v*)&Bl[(wv * 16 + ln15) * 40 + quad * 8];
        #pragma unroll
        for (int i = 0; i < 8; ++i) {
            s8v mh = *(s8v*)&Ah[(i * 16 + ln15) * 40 + quad * 8];
            s8v ml = *(s8v*)&Al[(i * 16 + ln15) * 40 + quad * 8];
            acc[i] = __builtin_amdgcn_mfma_f32_16x16x32_bf16(mh, qh, acc[i], 0, 0, 0);
            acc[i] = __builtin_amdgcn_mfma_f32_16x16x32_bf16(mh, ql, acc[i], 0, 0, 0);
            acc[i] = __builtin_amdgcn_mfma_f32_16x16x32_bf16(ml, qh, acc[i], 0, 0, 0);
        }
    }

    u64 l[9];
    #pragma unroll
    for (int i = 0; i < 9; ++i) l[i] = ~0ULL;
    #pragma unroll
    for (int i = 0; i < 8; ++i) {
        #pragma unroll
        for (int r = 0; r < 4; ++r) {
            int mloc = i * 16 + quad * 4 + r;
            float d = x2s[mloc] - 2.f * acc[i][r];
            unsigned u = __float_as_uint(d);
            u = (u & 0x80000000u) ? ~u : (u | 0x80000000u);
            u64 key = ((u64)u << 32) | (unsigned)(mq * 128 + mloc);
            if (key < l[8]) {
                u64 x = key;
                #pragma unroll
                for (int jj = 0; jj < 9; ++jj) {
                    u64 lo2 = l[jj] < x ? l[jj] : x;
                    u64 hi2 = l[jj] < x ? x : l[jj];
                    l[jj] = lo2; x = hi2;
                }
            }
        }
    }

    __syncthreads();
    {
        int qloc = wv * 16 + ln15;
        #pragma unroll
        for (int k = 0; k < 9; ++k) mrg[(qloc * 4 + quad) * 9 + k] = l[k];
    }
    __syncthreads();
    if (t < 128) {
        int r = t >> 1, pr = t & 1;
        const u64* LA = &mrg[(r * 4 + pr * 2) * 9];
        const u64* LB = LA + 9;
        int ia = 0, ib = 0;
        u64* Po = &mrg2[(r * 2 + pr) * 9];
        #pragma unroll
        for (int k = 0; k < 9; ++k) {
            u64 va = LA[ia], vb = LB[ib];
            bool ta = va < vb;
            Po[k] = ta ? va : vb;
            ia += ta; ib += !ta;
        }
    }
    __syncthreads();
    if (t < 64) {
        const u64* LA = &mrg2[(t * 2) * 9];
        const u64* LB = LA + 9;
        int ia = 0, ib = 0;
        u64* P = Part + (((long long)((b << 10) + q0 + t)) * 8 + mq) * 9;
        #pragma unroll
        for (int k = 0; k < 9; ++k) {
            u64 va = LA[ia], vb = LB[ib];
            bool ta = va < vb;
            P[k] = ta ? va : vb;
            ia += ta; ib += !ta;
        }
    }
}

// ---------------------------------------------------------------------------
// build_Mt + fused 8-list merge (UNCHANGED from R11 — verified).
// ---------------------------------------------------------------------------
__global__ __launch_bounds__(256)
void build_Mt(const float* __restrict__ Ft, const u64* __restrict__ Part,
              short* __restrict__ Mt)
{
    int t = threadIdx.x;
    int wv = t >> 6, lane = t & 63;
    int n = blockIdx.x * 4 + wv;
    int b = blockIdx.y;
    long long nb = (long long)(b << 10) + n;

    const u64* L = Part + nb * 72 + (long long)(lane & 7) * 9;
    u64 l[9];
    #pragma unroll
    for (int k = 0; k < 9; ++k) l[k] = L[k];
    #pragma unroll
    for (int s = 1; s <= 4; s <<= 1) {
        u64 p[9];
        #pragma unroll
        for (int k = 0; k < 9; ++k) p[k] = shfl_xor_u64(l[k], s);
        #pragma unroll
        for (int k = 0; k < 9; ++k) {
            u64 x = p[k];
            if (x < l[8]) {
                #pragma unroll
                for (int jj = 0; jj < 9; ++jj) {
                    u64 lo2 = l[jj] < x ? l[jj] : x;
                    u64 hi2 = l[jj] < x ? x : l[jj];
                    l[jj] = lo2; x = hi2;
                }
            }
        }
    }

    int c0 = lane * 4;
    f4v f = *(const f4v*)(Ft + nb * C_ + c0);
    f4v mx = {-3.4e38f, -3.4e38f, -3.4e38f, -3.4e38f};
    #pragma unroll
    for (int k = 0; k < 9; ++k) {
        int id = (int)(l[k] & 0xFFFFFFFFu);
        f4v g = *(const f4v*)(Ft + ((long long)(b << 10) + id) * C_ + c0);
        mx[0] = fmaxf(mx[0], g[0]); mx[1] = fmaxf(mx[1], g[1]);
        mx[2] = fmaxf(mx[2], g[2]); mx[3] = fmaxf(mx[3], g[3]);
    }
    s8v m8;
    #pragma unroll
    for (int r = 0; r < 4; ++r) {
        m8[2 * r]     = (short)f2b(f[r]);
        m8[2 * r + 1] = (short)f2b(mx[r] - f[r]);
    }
    *(s8v*)(Mt + nb * (2 * C_) + 2 * c0) = m8;
}

// ---------------------------------------------------------------------------
// MFMA GEMM retiled (gram-v4 geometry): 128 o x 64 n per block.
// A-operand = weight rows (o), B-operand = Bm rows (n); lane-col = fixed n.
// K-accumulation order identical to previous version -> bit-identical out.
// EPI 0: gelu(acc*s+t) -> bf16 Gt[b][n][Odim]
// EPI 1: acc*s+t + resid -> fp32 out[b][o][1024]
// ---------------------------------------------------------------------------
template<int EPI>
__global__ __launch_bounds__(256)
void mfma_gemm(const short* __restrict__ A, const short* __restrict__ Bm,
               void* __restrict__ Out, const float* __restrict__ scale,
               const float* __restrict__ bias, const void* __restrict__ resid,
               const int* __restrict__ flags, int K, int Odim)
{
    __shared__ __align__(16) short As[128 * 40];
    __shared__ __align__(16) short Bs[64 * 40];

    int t = threadIdx.x, b = blockIdx.z;
    int n0 = blockIdx.x * 64, o0 = blockIdx.y * 128;
    int wv = t >> 6, ln15 = t & 15, quad = (t >> 4) & 3;

    f4v acc[8];
    #pragma unroll
    for (int i = 0; i < 8; ++i) acc[i] = 0.f;

    int nkc = K >> 5;
    for (int kc = 0; kc < nkc; ++kc) {
        __syncthreads();
        #pragma unroll
        for (int s = 0; s < 3; ++s) {
            int sid = t + s * 256;            // 0..767
            int row = sid >> 2, seg = sid & 3;
            if (row < 128)
                *(s8v*)&As[row * 40 + seg * 8] =
                    *(const s8v*)(A + (long long)(o0 + row) * K + kc * 32 + seg * 8);
            else
                *(s8v*)&Bs[(row - 128) * 40 + seg * 8] =
                    *(const s8v*)(Bm + ((long long)((b << 10) + n0 + row - 128)) * K + kc * 32 + seg * 8);
        }
        __syncthreads();
        s8v bf = *(s8v*)&Bs[(wv * 16 + ln15) * 40 + quad * 8];
        #pragma unroll
        for (int i = 0; i < 8; ++i) {
            s8v a = *(s8v*)&As[(i * 16 + ln15) * 40 + quad * 8];
            acc[i] = __builtin_amdgcn_mfma_f32_16x16x32_bf16(a, bf, acc[i], 0, 0, 0);
        }
    }

    int inf = flags[0];
    int n = n0 + wv * 16 + ln15;
    #pragma unroll
    for (int i = 0; i < 8; ++i) {
        int ob = o0 + i * 16 + quad * 4;
        if (EPI == 0) {
            s4v g;
            #pragma unroll
            for (int r = 0; r < 4; ++r) {
                float val = acc[i][r] * scale[ob + r] + bias[ob + r];
                val = 0.5f * val * (1.0f + erff(val * 0.70710678118654752f));
                g[r] = (short)f2b(val);
            }
            *(s4v*)((short*)Out + ((long long)((b << 10) + n)) * Odim + ob) = g;
        } else {
            #pragma unroll
            for (int r = 0; r < 4; ++r) {
                int o = ob + r;
                long long oi = ((long long)b * Odim + o) * N_ + n;
                ((float*)Out)[oi] = acc[i][r] * scale[o] + bias[o] + ldIn(resid, oi, inf);
            }
        }
    }
}

// ---------------------------------------------------------------------------
extern "C" void kernel_launch(void* const* d_in, const int* in_sizes, int n_in,
                              void* d_out, int out_size, void* d_ws, size_t ws_size,
                              hipStream_t stream)
{
    const void* p[23];
    if (n_in >= 23 && in_sizes[0] != 4194304 && in_sizes[22] == 4194304) {
        const int amap[23] = {
            22, 13, 12, 1, 0, 2, 3,
            21, 20, 17, 16, 18, 19,
            5, 4, 6, 7,
            15, 14, 9, 8, 10, 11 };
        for (int i = 0; i < 23; ++i) p[i] = d_in[amap[i]];
    } else {
        for (int i = 0; i < 23; ++i) p[i] = d_in[i];
    }

    const void* x     = p[0];
    const void* fc1_w = p[1];
    const void* fc1_b = p[2];
    const void* bn1_g = p[3];
    const void* bn1_b = p[4];
    const void* bn1_m = p[5];
    const void* bn1_v = p[6];
    const void* gc_w  = p[7];
    const void* gc_b  = p[8];
    const void* gbn_g = p[9];
    const void* gbn_b = p[10];
    const void* gbn_m = p[11];
    const void* gbn_v = p[12];
    const void* bn2_g = p[13];
    const void* bn2_b = p[14];
    const void* bn2_m = p[15];
    const void* bn2_v = p[16];
    const void* fc2_w = p[17];
    const void* fc2_b = p[18];
    const void* bn3_g = p[19];
    const void* bn3_b = p[20];
    const void* bn3_m = p[21];
    const void* bn3_v = p[22];

    char* ws = (char*)d_ws;
    size_t off = 0;
    int*   flags = (int*)ws;
    float* s1 = (float*)(ws + 256);
    float* t1 = s1 + 256;
    float* s3 = t1 + 256;
    float* t3 = s3 + 256;
    float* Sg = t3 + 256;
    float* Tg = Sg + 512;
    off = 16384;
    short* W1h   = (short*)(ws + off); off += (size_t)C_ * C_ * 2;          // 128 KiB
    short* W1l   = (short*)(ws + off); off += (size_t)C_ * C_ * 2;          // 128 KiB
    short* Wgb   = (short*)(ws + off); off += (size_t)HID_ * 2 * C_ * 2;    // 512 KiB
    short* W2b   = (short*)(ws + off); off += (size_t)C_ * HID_ * 2;        // 256 KiB
    short* xth   = (short*)(ws + off); off += (size_t)B_ * N_ * C_ * 2;     // 8 MiB
    short* xtl   = (short*)(ws + off); off += (size_t)B_ * N_ * C_ * 2;     // 8 MiB
    float* Ft    = (float*)(ws + off); off += (size_t)B_ * N_ * C_ * 4;     // 16 MiB
    short* Fhi   = (short*)(ws + off); off += (size_t)B_ * N_ * C_ * 2;     // 8 MiB
    short* Flo   = (short*)(ws + off); off += (size_t)B_ * N_ * C_ * 2;     // 8 MiB
    float* x2    = (float*)(ws + off); off += (size_t)B_ * N_ * 4;          // 64 KiB
    u64*   Part  = (u64*)  (ws + off); off += (size_t)B_ * N_ * 8 * 9 * 8;  // 9 MiB
    short* Mt    = (short*)(ws + off); off += (size_t)B_ * N_ * 2 * C_ * 2; // 16 MiB
    short* Gt    = (short*)(ws + off); off += (size_t)B_ * N_ * HID_ * 2;   // 16 MiB

    prep_kernel<<<1, 512, 0, stream>>>(x,
        fc1_b, bn1_g, bn1_b, bn1_m, bn1_v,
        gc_b, gbn_g, gbn_b, gbn_m, gbn_v,
        bn2_g, bn2_b, bn2_m, bn2_v,
        fc2_b, bn3_g, bn3_b, bn3_m, bn3_v,
        flags, s1, t1, Sg, Tg, s3, t3, x2);

    cast_weights<<<1792, 256, 0, stream>>>(fc1_w, gc_w, fc2_w,
                                           W1h, W1l, Wgb, W2b, flags);

    transpose_split_x<<<dim3(16, 4, 16), 256, 0, stream>>>(x, xth, xtl, flags);

    fc1_mfma<<<dim3(16, 2, 16), 256, 0, stream>>>(
        W1h, W1l, xth, xtl, s1, t1, Ft, Fhi, Flo, x2);

    gram_topk<<<dim3(16, 8, 16), 256, 0, stream>>>(Fhi, Flo, x2, Part);

    build_Mt<<<dim3(256, 16), 256, 0, stream>>>(Ft, Part, Mt);

    mfma_gemm<0><<<dim3(16, 4, 16), 256, 0, stream>>>(
        Wgb, Mt, Gt, Sg, Tg, nullptr, flags, 2 * C_, HID_);

    mfma_gemm<1><<<dim3(16, 2, 16), 256, 0, stream>>>(
        W2b, Gt, d_out, s3, t3, x, flags, HID_, C_);
}